// Round 1
// baseline (398.962 us; speedup 1.0000x reference)
//
#include <hip/hip_runtime.h>
#include <hip/hip_bf16.h>

#define BATCH 4096
#define TT 512
#define BT 16      // 16 batch rows/block: set A = rows 0..7, set B = rows 8..15
#define XS 516     // x_s row stride in floats
#define HS 72      // h buffer row stride in bf16

typedef __attribute__((ext_vector_type(8))) short short8;
typedef __attribute__((ext_vector_type(4))) float floatx4;
typedef __attribute__((ext_vector_type(2))) float float2v;

__device__ __forceinline__ unsigned short f2bf(float f) {   // RNE f32->bf16 (weights, one-time)
    unsigned u = __float_as_uint(f);
    u = u + 0x7FFFu + ((u >> 16) & 1u);
    return (unsigned short)(u >> 16);
}

// R16: dual-set anti-phase. R15 wall = VALU 537 + MFMA 294 + slack 183, strictly
// additive (in-phase convoy lock across blocks; act->h->barrier->MFMA serial in
// wave). Fix in-wave: two independent 8-row batch sets per block, half a step
// out of phase. While set X's MFMA chews in the matrix pipe, the wave issues
// set Y's activation VALU; LDS frag-read latency hides under the 8-exp2 block
// of the other set. sched_barrier(0) pins the 4 region boundaries per
// iteration (MFMAs are register-only and would otherwise sink past s_barrier
// toward their consumer). Grid 256 blocks -> 1 block/CU, 1 wave/SIMD; per-SIMD
// work identical to R15, but MFMA + LDS latency come off the critical path.
__global__ __launch_bounds__(256, 1) void lstm_kernel(
    const float* __restrict__ x, const float* __restrict__ W_ih,
    const float* __restrict__ W_hh, const float* __restrict__ b_ih,
    const float* __restrict__ b_hh, const float* __restrict__ W_out,
    const float* __restrict__ b_out, float* __restrict__ out)
{
    __shared__ __align__(16) float x_s[BT * XS];             // 33.0 KB
    __shared__ __align__(16) unsigned short hA[16 * HS];     // set A h(k); rows m&2 stay 0
    __shared__ __align__(16) unsigned short hB[16 * HS];     // set B h(k)
    __shared__ __align__(16) float hf[BT * 65];

    const int tid = threadIdx.x;
    const int w = tid >> 6;       // wave 0..3 -> gate col-tiles {w,w+4,w+8,w+12}
    const int l = tid & 63;
    const int q = l >> 4;
    const int c = l & 15;
    const int n = 16 * w + c;     // hidden index this lane activates
    const int bbase = blockIdx.x * BT;

    // stage x[bbase..bbase+15][0..511] into LDS, coalesced float4 (2048 float4s)
    for (int i = 0; i < 8; ++i) {
        int flat = i * 256 + tid;
        int row = flat >> 7, c4 = flat & 127;
        const float4* xg = reinterpret_cast<const float4*>(x + (size_t)(bbase + row) * TT);
        float4 v = xg[c4];
        *reinterpret_cast<float4*>(&x_s[row * XS + c4 * 4]) = v;
    }
    for (int i = tid; i < 16 * HS; i += 256) { hA[i] = 0; hB[i] = 0; }

    const float L1 = 1.44269504089f;      // log2(e)
    const float L2 = 2.88539008178f;      // 2*log2(e)

    // persistent B-fragments, PRE-SCALED: t=0(i),1(f),3(o): -log2e ; t=2(g): +2log2e
    short8 bfr[4][2];
    float2v wih2[4], bb2[4];
    for (int t = 0; t < 4; ++t) {
        float sc = (t == 2) ? L2 : -L1;
        int g = 64 * t + n;
        float wv = W_ih[g] * sc;
        float bv = (b_ih[g] + b_hh[g]) * sc;
        wih2[t] = float2v{wv, wv};
        bb2[t] = float2v{bv, bv};
        for (int ks = 0; ks < 2; ++ks) {
            const float* wp = W_hh + g * 64 + ks * 32 + q * 8;
            short8 v;
            #pragma unroll
            for (int j = 0; j < 8; ++j) v[j] = (short)f2bf(wp[j] * sc);
            bfr[t][ks] = v;
        }
    }

    float2v cA = {0.f, 0.f}, cB = {0.f, 0.f};   // c-state per set, rows {2q,2q+1} of set
    const float2v one2 = {1.f, 1.f};
    const float2v L2v = {L2, L2};

    floatx4 accA[4], accB[4];     // slots r=2,3 face zero A-rows: init once, stay 0
    #pragma unroll
    for (int t = 0; t < 4; ++t) {
        accA[t] = floatx4{0.f, 0.f, 0.f, 0.f};
        accB[t] = floatx4{0.f, 0.f, 0.f, 0.f};
    }

    const int aoff = c * HS + q * 8;      // A-frag LDS offset (shorts)
    const int woff = (4 * q) * HS + n;    // h write base; +HS for second row
    const float* xA0 = &x_s[(2 * q) * XS];
    const float* xA1 = &x_s[(2 * q + 1) * XS];
    const float* xB0 = &x_s[(8 + 2 * q) * XS];
    const float* xB1 = &x_s[(9 + 2 * q) * XS];

    __syncthreads();   // staging + zeroed h visible

    // prologue: accB = gates_B(0) = x_projB(0)  (h(-1)=0, no MFMA)
    {
        float2v x01 = {xB0[0], xB1[0]};
        #pragma unroll
        for (int t = 0; t < 4; ++t) {
            float2v a2 = x01 * wih2[t] + bb2[t];
            accB[t][0] = a2.x; accB[t][1] = a2.y;
        }
    }
    short8 fa0 = *reinterpret_cast<const short8*>(hA + aoff);       // zeros
    short8 fa1 = *reinterpret_cast<const short8*>(hA + aoff + 32);

    // 8 independent exp2 of one set's gates (trans-pipe block; also the latency
    // cover for LDS reads issued just before it)
    #define EXPM(ACC, EI, EF, EG, EO) do {                                      \
        EI.x = __builtin_amdgcn_exp2f(ACC[0][0]);                               \
        EI.y = __builtin_amdgcn_exp2f(ACC[0][1]);                               \
        EF.x = __builtin_amdgcn_exp2f(ACC[1][0]);                               \
        EF.y = __builtin_amdgcn_exp2f(ACC[1][1]);                               \
        EG.x = __builtin_amdgcn_exp2f(ACC[2][0]);                               \
        EG.y = __builtin_amdgcn_exp2f(ACC[2][1]);                               \
        EO.x = __builtin_amdgcn_exp2f(ACC[3][0]);                               \
        EO.y = __builtin_amdgcn_exp2f(ACC[3][1]);                               \
    } while (0)

    // rest of the packed activation: algebra + 2 exp2 + 2 rcp -> h (float2v)
    #define RESTM(EI, EF, EG, EO, CST, HV) do {                                 \
        float2v pf2 = (EF) + one2;                                              \
        float2v pg2 = ((EI) + one2) * ((EG) + one2);                            \
        float2v d2 = pf2 * pg2;                                                 \
        float rd = __builtin_amdgcn_rcpf(d2.x * d2.y);                          \
        float2v num2 = (CST) * pg2 + ((EG) - one2) * pf2;                       \
        float2v dsw = {d2.y, d2.x};                                             \
        CST = num2 * dsw * rd;                                                  \
        float2v l2c = (CST) * L2v;                                              \
        float2v ec2;                                                            \
        ec2.x = __builtin_amdgcn_exp2f(l2c.x);                                  \
        ec2.y = __builtin_amdgcn_exp2f(l2c.y);                                  \
        float2v e2 = ((EO) + one2) * (ec2 + one2);                              \
        float re = __builtin_amdgcn_rcpf(e2.x * e2.y);                          \
        float2v esw = {e2.y, e2.x};                                             \
        HV = (ec2 - one2) * esw * re;                                           \
    } while (0)

    #define INIT2(ACC, X01) do {                                                \
        _Pragma("unroll")                                                       \
        for (int t = 0; t < 4; ++t) {                                           \
            float2v a2 = (X01) * wih2[t] + bb2[t];                              \
            ACC[t][0] = a2.x; ACC[t][1] = a2.y;                                 \
        }                                                                       \
    } while (0)

    for (int k = 0; k < 511; ++k) {
        // ---- step 0: hoist xA(k) read (latency under EXP_B) ----
        float2v xA01 = {xA0[k], xA1[k]};
        // ---- step 1: EXP_B(k) -- acc_B ready since M_B(k) issued last iter ----
        float2v eiB, efB, egB, eoB;
        EXPM(accB, eiB, efB, egB, eoB);
        __builtin_amdgcn_sched_barrier(0);
        // ---- step 2: M_A(k): init + 8 MFMA from frags_A(k-1) ----
        INIT2(accA, xA01);
        #pragma unroll
        for (int t = 0; t < 4; ++t) {
            accA[t] = __builtin_amdgcn_mfma_f32_16x16x32_bf16(fa0, bfr[t][0], accA[t], 0, 0, 0);
            accA[t] = __builtin_amdgcn_mfma_f32_16x16x32_bf16(fa1, bfr[t][1], accA[t], 0, 0, 0);
        }
        __builtin_amdgcn_sched_barrier(0);
        // ---- step 3: REST_B -> h_B(k), packed bf16 write ----
        {
            float2v hvB;
            RESTM(eiB, efB, egB, eoB, cB, hvB);
            __hip_bfloat162 hpk = __float22bfloat162_rn(float2{hvB.x, hvB.y});
            hB[woff]      = *reinterpret_cast<unsigned short*>(&hpk.x);
            hB[woff + HS] = *reinterpret_cast<unsigned short*>(&hpk.y);
        }
        __syncthreads();                                  // h_B(k) visible
        // ---- step 5: R_B + xB(k+1) reads (latency under EXP_A) ----
        short8 fb0 = *reinterpret_cast<const short8*>(hB + aoff);
        short8 fb1 = *reinterpret_cast<const short8*>(hB + aoff + 32);
        float2v xB01 = {xB0[k + 1], xB1[k + 1]};
        // ---- step 6: EXP_A(k) -- M_A issued ~160+ cyc ago ----
        float2v eiA, efA, egA, eoA;
        EXPM(accA, eiA, efA, egA, eoA);
        __builtin_amdgcn_sched_barrier(0);
        // ---- step 7: M_B(k+1): init + 8 MFMA from frags_B(k) ----
        INIT2(accB, xB01);
        #pragma unroll
        for (int t = 0; t < 4; ++t) {
            accB[t] = __builtin_amdgcn_mfma_f32_16x16x32_bf16(fb0, bfr[t][0], accB[t], 0, 0, 0);
            accB[t] = __builtin_amdgcn_mfma_f32_16x16x32_bf16(fb1, bfr[t][1], accB[t], 0, 0, 0);
        }
        __builtin_amdgcn_sched_barrier(0);
        // ---- step 8: REST_A -> h_A(k) ----
        {
            float2v hvA;
            RESTM(eiA, efA, egA, eoA, cA, hvA);
            __hip_bfloat162 hpk = __float22bfloat162_rn(float2{hvA.x, hvA.y});
            hA[woff]      = *reinterpret_cast<unsigned short*>(&hpk.x);
            hA[woff + HS] = *reinterpret_cast<unsigned short*>(&hpk.y);
        }
        __syncthreads();                                  // h_A(k) visible
        // ---- step 10: R_A: frags_A(k) for next iteration's M_A ----
        fa0 = *reinterpret_cast<const short8*>(hA + aoff);
        fa1 = *reinterpret_cast<const short8*>(hA + aoff + 32);
    }

    // ---- epilogue: t=511. Issue M_A(511) first, hide it under ACT_B(511). ----
    {
        float2v xA01 = {xA0[511], xA1[511]};
        INIT2(accA, xA01);
        #pragma unroll
        for (int t = 0; t < 4; ++t) {
            accA[t] = __builtin_amdgcn_mfma_f32_16x16x32_bf16(fa0, bfr[t][0], accA[t], 0, 0, 0);
            accA[t] = __builtin_amdgcn_mfma_f32_16x16x32_bf16(fa1, bfr[t][1], accA[t], 0, 0, 0);
        }
    }
    {
        float2v eiB, efB, egB, eoB, hvB;
        EXPM(accB, eiB, efB, egB, eoB);     // acc_B = gates_B(511) from last M_B
        RESTM(eiB, efB, egB, eoB, cB, hvB);
        hf[(8 + 2 * q) * 65 + n] = hvB.x;
        hf[(9 + 2 * q) * 65 + n] = hvB.y;
    }
    {
        float2v eiA, efA, egA, eoA, hvA;
        EXPM(accA, eiA, efA, egA, eoA);
        RESTM(eiA, efA, egA, eoA, cA, hvA);
        hf[(2 * q) * 65 + n] = hvA.x;
        hf[(2 * q + 1) * 65 + n] = hvA.y;
    }
    __syncthreads();

    // head: out[b][o] = sum_n hf[b][n]*W_out[o][n] + b_out[o]
    if (tid < BT * 3) {
        int row = tid / 3, o = tid % 3;
        float s = b_out[o];
        #pragma unroll 8
        for (int kk = 0; kk < 64; ++kk) s = fmaf(hf[row * 65 + kk], W_out[o * 64 + kk], s);
        out[(size_t)(bbase + row) * 3 + o] = s;
    }
    #undef EXPM
    #undef RESTM
    #undef INIT2
}

extern "C" void kernel_launch(void* const* d_in, const int* in_sizes, int n_in,
                              void* d_out, int out_size, void* d_ws, size_t ws_size,
                              hipStream_t stream) {
    const float* x     = (const float*)d_in[0];
    const float* W_ih  = (const float*)d_in[1];
    const float* W_hh  = (const float*)d_in[2];
    const float* b_ih  = (const float*)d_in[3];
    const float* b_hh  = (const float*)d_in[4];
    const float* W_out = (const float*)d_in[5];
    const float* b_out = (const float*)d_in[6];
    float* out = (float*)d_out;
    hipLaunchKernelGGL(lstm_kernel, dim3(BATCH / BT), dim3(256), 0, stream,
                       x, W_ih, W_hh, b_ih, b_hh, W_out, b_out, out);
}

// Round 2
// 252.849 us; speedup vs baseline: 1.5779x; 1.5779x over previous
//
#include <hip/hip_runtime.h>
#include <hip/hip_bf16.h>

#define BATCH 4096
#define TT 512
#define HH 64
#define BT 8       // batch rows per block; batch j at tile row 4*(j>>1)+(j&1) -> valid C/D slots r=0,1
#define XS 516     // x_s row stride in floats
#define HS 72      // h buffer row stride in bf16

typedef __attribute__((ext_vector_type(8))) short short8;
typedef __attribute__((ext_vector_type(4))) float floatx4;
typedef __attribute__((ext_vector_type(2))) float float2v;

__device__ __forceinline__ unsigned short f2bf(float f) {   // RNE f32->bf16 (weights, one-time)
    unsigned u = __float_as_uint(f);
    u = u + 0x7FFFu + ((u >> 16) & 1u);
    return (unsigned short)(u >> 16);
}

// R17: R15 structure (known 203 us: wall 951 = VALU 505 + MFMA 276 + slack 170)
// + per-CU de-convoy ticket. R16 proved 1-wave/SIMD anti-phase loses (slack
// 170->672: no TLP to cover REST chain + barrier + ds_read latency). R15's
// additive pipes come from phase-locked co-resident blocks: they launch
// together, run identical code, and Delta=0 is conserved. So: perturb once.
// Each block reads its physical CU id (HW_ID CU/SH/SE + XCC_ID), takes an
// atomic ticket in workspace; second arrival on a CU sleeps ~384 cyc. The
// offset persists (issue-bound contention stretches both blocks equally),
// putting one block's MFMA burst under the other's ACT VALU window.
__global__ __launch_bounds__(256, 2) void lstm_kernel(
    const float* __restrict__ x, const float* __restrict__ W_ih,
    const float* __restrict__ W_hh, const float* __restrict__ b_ih,
    const float* __restrict__ b_hh, const float* __restrict__ W_out,
    const float* __restrict__ b_out, float* __restrict__ out,
    unsigned int* __restrict__ ticket)
{
    __shared__ __align__(16) float x_s[BT * XS];             // 16.5 KB
    __shared__ __align__(16) unsigned short hb0[16 * HS];    // h_k, k even; rows m&2 stay 0
    __shared__ __align__(16) unsigned short hb1[16 * HS];    // h_k, k odd
    __shared__ __align__(16) float hf[BT * 65];
    __shared__ int sflag;

    const int tid = threadIdx.x;
    const int w = tid >> 6;       // wave 0..3 -> gate col-tiles {w,w+4,w+8,w+12}
    const int l = tid & 63;
    const int q = l >> 4;
    const int c = l & 15;
    const int n = 16 * w + c;     // hidden index this lane activates
    const int bbase = blockIdx.x * BT;

    // stage x[bbase..bbase+7][0..511] into LDS, coalesced float4
    for (int i = 0; i < 4; ++i) {
        int flat = i * 256 + tid;              // 1024 float4s
        int row = flat >> 7, c4 = flat & 127;
        const float4* xg = reinterpret_cast<const float4*>(x + (size_t)(bbase + row) * TT);
        float4 v = xg[c4];
        *reinterpret_cast<float4*>(&x_s[row * XS + c4 * 4]) = v;
    }
    for (int i = tid; i < 16 * HS; i += 256) { hb0[i] = 0; hb1[i] = 0; }

    // de-convoy ticket: unique physical-CU slot; 2nd co-resident block delays.
    if (tid == 0) {
        int fl = 0;
        if (ticket) {
            // HW_ID (id=4), full 32b: CU_ID[11:8] SH_ID[12] SE_ID[15:13]
            unsigned hwid = (unsigned)__builtin_amdgcn_s_getreg(63492);  // 4 | (31<<11)
            // XCC_ID (id=20), full 32b
            unsigned xcc  = (unsigned)__builtin_amdgcn_s_getreg(63508);  // 20 | (31<<11)
            unsigned idx = ((xcc & 7u) << 8) | ((hwid >> 8) & 0xFFu);    // 0..2047
            unsigned t = atomicAdd(&ticket[idx], 1u);
            fl = (int)(t & 1u);
        }
        sflag = fl;
    }

    const float L1 = 1.44269504089f;      // log2(e)
    const float L2 = 2.88539008178f;      // 2*log2(e)

    // persistent B-fragments, PRE-SCALED: t=0(i),1(f),3(o): -log2e ; t=2(g): +2log2e
    short8 bfr[4][2];
    float2v wih2[4], bb2[4];              // broadcast pairs for pk_fma acc-init
    for (int t = 0; t < 4; ++t) {
        float sc = (t == 2) ? L2 : -L1;
        int g = 64 * t + n;
        float wv = W_ih[g] * sc;
        float bv = (b_ih[g] + b_hh[g]) * sc;
        wih2[t] = float2v{wv, wv};
        bb2[t] = float2v{bv, bv};
        for (int ks = 0; ks < 2; ++ks) {
            const float* wp = W_hh + g * 64 + ks * 32 + q * 8;
            short8 v;
            #pragma unroll
            for (int j = 0; j < 8; ++j) v[j] = (short)f2bf(wp[j] * sc);
            bfr[t][ks] = v;
        }
    }

    float2v cst2 = {0.f, 0.f};    // c-state, batch rows {2q, 2q+1}, hidden n
    float2v hv2 = {0.f, 0.f};     // current h (register)
    const float2v one2 = {1.f, 1.f};
    const float2v L2v = {L2, L2};

    floatx4 acc[4];               // slots r=2,3 face zero A-rows: init once, stay 0
    #pragma unroll
    for (int t = 0; t < 4; ++t) acc[t] = floatx4{0.f, 0.f, 0.f, 0.f};

    const int aoff = c * HS + q * 8;      // A-frag LDS offset (shorts)
    const int woff = (4 * q) * HS + n;    // h write base; +HS for cell 1
    const float* xrowA = &x_s[(2 * q) * XS];
    const float* xrowB = &x_s[(2 * q + 1) * XS];

    __syncthreads();   // staging + zeroed h0 + sflag visible

    // phase offset: ~384 cyc for the second block on this CU
    if (sflag) __builtin_amdgcn_s_sleep(6);

    // Prologue: gates(0) = x_proj only (h(-1)=0 -> no MFMA needed)
    {
        float2v x01 = {xrowA[0], xrowB[0]};
        #pragma unroll
        for (int t = 0; t < 4; ++t) {
            float2v a2 = x01 * wih2[t] + bb2[t];
            acc[t][0] = a2.x; acc[t][1] = a2.y;
        }
    }

    // packed act: 10 scalar exp2 -> float2v algebra (pk ops) -> 2 scalar rcp
    #define ACTP() do {                                                         \
        float2v ei2, ef2, eg2, eo2;                                             \
        ei2.x = __builtin_amdgcn_exp2f(acc[0][0]);                              \
        ei2.y = __builtin_amdgcn_exp2f(acc[0][1]);                              \
        ef2.x = __builtin_amdgcn_exp2f(acc[1][0]);                              \
        ef2.y = __builtin_amdgcn_exp2f(acc[1][1]);                              \
        eg2.x = __builtin_amdgcn_exp2f(acc[2][0]);                              \
        eg2.y = __builtin_amdgcn_exp2f(acc[2][1]);                              \
        eo2.x = __builtin_amdgcn_exp2f(acc[3][0]);                              \
        eo2.y = __builtin_amdgcn_exp2f(acc[3][1]);                              \
        float2v pf2 = ef2 + one2;                                               \
        float2v pg2 = (ei2 + one2) * (eg2 + one2);                              \
        float2v d2 = pf2 * pg2;                                                 \
        float rd = __builtin_amdgcn_rcpf(d2.x * d2.y);                          \
        float2v num2 = cst2 * pg2 + (eg2 - one2) * pf2;                         \
        float2v dsw = {d2.y, d2.x};                                             \
        cst2 = num2 * dsw * rd;                                                 \
        float2v l2c = cst2 * L2v;                                               \
        float2v ec2;                                                            \
        ec2.x = __builtin_amdgcn_exp2f(l2c.x);                                  \
        ec2.y = __builtin_amdgcn_exp2f(l2c.y);                                  \
        float2v e2 = (eo2 + one2) * (ec2 + one2);                               \
        float re = __builtin_amdgcn_rcpf(e2.x * e2.y);                          \
        float2v esw = {e2.y, e2.x};                                             \
        hv2 = (ec2 - one2) * esw * re;                                          \
    } while (0)

    // one pipelined step: act(k) -> packed h write -> barrier -> frag read +
    // MFMA(k+1). dst is a compile-time constant pointer at each call site.
    auto step = [&](int k, unsigned short* dst) {
        ACTP();
        // one v_cvt_pk_bf16_f32; stores lower to b16, upper to b16_d16_hi
        __hip_bfloat162 hpk = __float22bfloat162_rn(float2{hv2.x, hv2.y});
        dst[woff]      = *reinterpret_cast<unsigned short*>(&hpk.x);
        dst[woff + HS] = *reinterpret_cast<unsigned short*>(&hpk.y);

        // hoist x(k+1) LDS reads: latency hides under the barrier
        float2v x01 = {xrowA[k + 1], xrowB[k + 1]};

        __syncthreads();

        short8 a0 = *reinterpret_cast<const short8*>(dst + aoff);
        short8 a1 = *reinterpret_cast<const short8*>(dst + aoff + 32);
        #pragma unroll
        for (int t = 0; t < 4; ++t) {
            float2v a2 = x01 * wih2[t] + bb2[t];
            acc[t][0] = a2.x; acc[t][1] = a2.y;
        }
        #pragma unroll
        for (int t = 0; t < 4; ++t) {
            acc[t] = __builtin_amdgcn_mfma_f32_16x16x32_bf16(a0, bfr[t][0], acc[t], 0, 0, 0);
            acc[t] = __builtin_amdgcn_mfma_f32_16x16x32_bf16(a1, bfr[t][1], acc[t], 0, 0, 0);
        }
    };

    // steps 0..510 pipelined (write h(k), issue MFMA(k+1)); manual 2x unroll
    for (int k = 0; k < 510; k += 2) {
        step(k, hb0);         // even k -> hb0
        step(k + 1, hb1);     // odd  k -> hb1
    }
    step(510, hb0);

    // ---- final act(511) ----
    ACTP();

    hf[(2 * q) * 65 + n] = hv2.x;
    hf[(2 * q + 1) * 65 + n] = hv2.y;
    __syncthreads();

    // head: out[b][o] = sum_n hf[b][n]*W_out[o][n] + b_out[o]
    if (tid < BT * 3) {
        int row = tid / 3, o = tid % 3;
        float s = b_out[o];
        #pragma unroll 8
        for (int k = 0; k < HH; ++k) s = fmaf(hf[row * 65 + k], W_out[o * 64 + k], s);
        out[(size_t)(bbase + row) * 3 + o] = s;
    }
    #undef ACTP
}

extern "C" void kernel_launch(void* const* d_in, const int* in_sizes, int n_in,
                              void* d_out, int out_size, void* d_ws, size_t ws_size,
                              hipStream_t stream) {
    const float* x     = (const float*)d_in[0];
    const float* W_ih  = (const float*)d_in[1];
    const float* W_hh  = (const float*)d_in[2];
    const float* b_ih  = (const float*)d_in[3];
    const float* b_hh  = (const float*)d_in[4];
    const float* W_out = (const float*)d_in[5];
    const float* b_out = (const float*)d_in[6];
    float* out = (float*)d_out;
    unsigned int* ticket = (ws_size >= 2048 * sizeof(unsigned int))
                               ? (unsigned int*)d_ws : nullptr;
    hipLaunchKernelGGL(lstm_kernel, dim3(BATCH / BT), dim3(256), 0, stream,
                       x, W_ih, W_hh, b_ih, b_hh, W_out, b_out, out, ticket);
}